// Round 4
// baseline (9697.560 us; speedup 1.0000x reference)
//
#include <hip/hip_runtime.h>
#include <stdint.h>
#include <stddef.h>

// ===================== problem constants =====================
#define LT    2048
#define BATCH 64
#define NH    256
#define HS_ELEMS  (BATCH * LT * NH)   // 33554432
#define OUT_ELEMS (BATCH * LT * 2)    // 262144
// d_out layout: [hs (B,L,256) | outs (B,L,2) | priors (B,L,16)] fp32

typedef __attribute__((ext_vector_type(8))) __bf16 bf16x8;
typedef __attribute__((ext_vector_type(4))) float  f32x4;
typedef __attribute__((ext_vector_type(2))) unsigned u32x2;

// v_cvt_pk_bf16_f32: dst = {lo16: bf16(a), hi16: bf16(b)}, RNE
static __device__ __forceinline__ unsigned pk2(float a, float b) {
  unsigned r;
  asm("v_cvt_pk_bf16_f32 %0, %1, %2" : "=v"(r) : "v"(a), "v"(b));
  return r;
}
static __device__ __forceinline__ bf16x8 pack8v(f32x4 a, f32x4 b) {
  union { unsigned u[4]; bf16x8 v; } r;
  r.u[0] = pk2(a[0], a[1]); r.u[1] = pk2(a[2], a[3]);
  r.u[2] = pk2(b[0], b[1]); r.u[3] = pk2(b[2], b[3]);
  return r.v;
}
static __device__ __forceinline__ bf16x8 pack8(const float* p) {
  return pack8v(*(const f32x4*)p, *(const f32x4*)(p + 4));
}
static __device__ __forceinline__ bf16x8 zero8() {
  union { unsigned u[4]; bf16x8 v; } r;
  r.u[0] = r.u[1] = r.u[2] = r.u[3] = 0u;
  return r.v;
}
// XOR swizzle on byte offsets (bits 4..6 by row&7, bit 5 extra by row bit 3)
static __device__ __forceinline__ int swz(int row, int off) {
  return off ^ ((row & 7) << 4) ^ (((row >> 3) & 1) << 5);
}

// Raw workgroup barrier: LDS ordered via lgkmcnt(0); vmcnt deliberately NOT
// drained (global loads/stores stay in flight across the barrier).
#define BARRIER() do {                                           \
    asm volatile("s_waitcnt lgkmcnt(0)" ::: "memory");           \
    __builtin_amdgcn_s_barrier();                                \
    asm volatile("" ::: "memory");                               \
  } while (0)

// LDS layout (bytes) for the serial kernel
#define W_RES_OFF 0        // 256 rows x 512B  (W_res[n][k] bf16, swizzled)
#define A_S_OFF   131072   // 16 rows x 1024B  (h bf16 at [0,512), r at [512,1024))
#define W_PR_OFF  147456   // 16 rows x 512B   (W_pr[n][k] bf16, swizzled)
#define X_OFF     155648   // 16 rows x 128B   (x_t bf16 padded to k=32, swizzled)
#define BIASR_OFF 157696   // 64 x f32x4: (b_fs+b_res)
#define BIASH_OFF 158720   // 64 x f32x4: (b_in+b_hh+b_sf)
#define BP_OFF    159744   // 4 x f32x4: b_pr
#define LDS_BYTES 159808

// ===================== kernel 1: the serial recurrence =====================
// 8 waves x 64 lanes; wave owns 32 output cols (2 tiles of 16) for tmp_h and
// tmp_r. Weights = MFMA A-operand (VGPR/AGPR), state = B-operand (LDS bf16).
// K is augmented: [h(256) | r(256) | x_t(32 padded)] -> 17 k-steps; the 9th
// wHH fragment is W_in. Nothing in this kernel READS hs -> h-stores are
// fire-and-forget; no per-step vmcnt drain anywhere.
__global__ __launch_bounds__(512, 2) void rnn_seq_kernel(
    const float* __restrict__ x,          // [B,L,16]
    const float* __restrict__ hidden,     // [B,256]
    const float* __restrict__ reservoir,  // [B,256]
    const float* __restrict__ noise,      // [L,B,256]
    const float* __restrict__ W_in, const float* __restrict__ b_in,
    const float* __restrict__ W_hh, const float* __restrict__ b_hh,
    const float* __restrict__ W_sf, const float* __restrict__ b_sf,
    const float* __restrict__ W_fs, const float* __restrict__ b_fs,
    const float* __restrict__ W_res, const float* __restrict__ b_res,
    const float* __restrict__ W_pr, const float* __restrict__ b_pr,
    float* __restrict__ hs,               // [B,L,256]
    float* __restrict__ priors)           // [B,L,16]
{
  extern __shared__ char lds[];
  const int tid  = threadIdx.x;
  const int lane = tid & 63;
  const int wv   = tid >> 6;        // wave 0..7
  const int col  = lane & 15;       // batch row within WG
  const int kg   = lane >> 4;       // k-group 0..3
  const int b0   = blockIdx.x * 16;

  // ---- stage W_res into LDS: [n][k] bf16, row-swizzled; 2 threads/row ----
  {
    const int n = tid >> 1, half = tid & 1;
    const float* src = W_res + (size_t)n * NH + half * 128;
    char* row = lds + W_RES_OFF + n * 512;
#pragma unroll 4
    for (int i = 0; i < 16; ++i)
      *(bf16x8*)(row + swz(n, half * 256 + i * 16)) = pack8(src + i * 8);
  }
  // ---- stage W_pr (16 rows), threads 0..255 ----
  if (tid < 256) {
    const int n = tid >> 4, seg = tid & 15;
    const float* src = W_pr + (size_t)n * NH + seg * 16;
    char* row = lds + W_PR_OFF + n * 512;
    *(bf16x8*)(row + swz(n, seg * 32))      = pack8(src);
    *(bf16x8*)(row + swz(n, seg * 32 + 16)) = pack8(src + 8);
  }
  // ---- stage initial state h0, r0 into A_s ([m][k], swizzled) ----
  {
    const int m = tid >> 5, seg = tid & 31;   // 8 floats each
    const float* hsrc = hidden    + (size_t)(b0 + m) * NH + seg * 8;
    const float* rsrc = reservoir + (size_t)(b0 + m) * NH + seg * 8;
    char* row = lds + A_S_OFF + m * 1024;
    *(bf16x8*)(row + swz(m, seg * 16))       = pack8(hsrc);
    *(bf16x8*)(row + swz(m, 512 + seg * 16)) = pack8(rsrc);
  }
  // ---- stage X region with x(0) (wave 7); kg>=2 granules = zeros forever --
  if (wv == 7) {
    char* xrow = lds + X_OFF + col * 128;
    if (kg < 2) {
      const float* xp = x + (size_t)(b0 + col) * LT * 16 + kg * 8;
      *(bf16x8*)(xrow + swz(col, kg * 16)) = pack8(xp);
    } else {
      *(bf16x8*)(xrow + swz(col, kg * 16)) = zero8();
    }
  }
  // ---- stage biases ----
  if (tid < 64) {
    f32x4 v = *(const f32x4*)(b_fs + tid * 4);
    f32x4 w = *(const f32x4*)(b_res + tid * 4);
    *(f32x4*)(lds + BIASR_OFF + tid * 16) = v + w;
  }
  if (tid >= 64 && tid < 128) {
    const int i = tid - 64;
    f32x4 v = *(const f32x4*)(b_in + i * 4);
    f32x4 w = *(const f32x4*)(b_hh + i * 4);
    f32x4 y = *(const f32x4*)(b_sf + i * 4);
    *(f32x4*)(lds + BIASH_OFF + i * 16) = v + w + y;
  }
  if (tid < 4)
    *(f32x4*)(lds + BP_OFF + tid * 16) = *(const f32x4*)(b_pr + tid * 4);

  // ---- per-lane weight fragments (A-operand), 2 tiles per wave ----
  // wHH has 9 frags: [0..7] = W_hh k-slices, [8] = W_in (k padded to 32).
  bf16x8 wHH[2][9], wSF[2][8], wFS[2][8];
#pragma unroll
  for (int tile = 0; tile < 2; ++tile) {
    const int n = wv * 32 + tile * 16 + col;
#pragma unroll
    for (int kk = 0; kk < 8; ++kk) {
      wHH[tile][kk] = pack8(W_hh + (size_t)n * NH + kk * 32 + kg * 8);
      wSF[tile][kk] = pack8(W_sf + (size_t)n * NH + kk * 32 + kg * 8);
      wFS[tile][kk] = pack8(W_fs + (size_t)n * NH + kk * 32 + kg * 8);
    }
    wHH[tile][8] = (kg < 2) ? pack8(W_in + (size_t)n * 16 + kg * 8) : zero8();
  }

  // ---- state / accumulators ----
  const size_t hsRow = (size_t)(b0 + col) * (LT * NH);
  const size_t nzRow = (size_t)(b0 + col) * NH;
  f32x4 r_old[2], accH[2], accR[2], accP;
#pragma unroll
  for (int tile = 0; tile < 2; ++tile) {
    const int nb = wv * 32 + tile * 16 + kg * 4;
    r_old[tile] = *(const f32x4*)(reservoir + nzRow + nb);
    accH[tile]  = *(const f32x4*)(lds + BIASH_OFF + nb * 4);
    accR[tile]  = *(const f32x4*)(lds + BIASR_OFF + nb * 4);
  }
  accP = *(const f32x4*)(lds + BP_OFF + kg * 16);

  BARRIER();   // staging visible to all waves

#pragma unroll 1
  for (int t = 0; t < LT; ++t) {
    // ---- prefetch: noise(t) for this epilogue; x(t+1) raw (wave 7) ----
    f32x4 nzc[2], xr0, xr1;
#pragma unroll
    for (int tile = 0; tile < 2; ++tile) {
      const int nb = wv * 32 + tile * 16 + kg * 4;
      nzc[tile] = *(const f32x4*)(noise + (size_t)t * (BATCH * NH) + nzRow + nb);
    }
    if (wv == 7) {
      const size_t tp1 = (t + 1 < LT) ? (size_t)(t + 1) : (size_t)(LT - 1);
      const float* xp = x + ((size_t)(b0 + col) * LT + tp1) * 16 + (kg & 1) * 8;
      xr0 = *(const f32x4*)xp;
      xr1 = *(const f32x4*)(xp + 4);
    }

    // -------- K-loop: K=512 over [h | r], 16 k-steps + x extension --------
#pragma unroll
    for (int kk = 0; kk < 16; ++kk) {
      const bf16x8 af = *(const bf16x8*)(lds + A_S_OFF + col * 1024 +
                                         swz(col, kk * 64 + kg * 16));
      if (kk < 8) {
#pragma unroll
        for (int tile = 0; tile < 2; ++tile)
          accH[tile] = __builtin_amdgcn_mfma_f32_16x16x32_bf16(wHH[tile][kk], af, accH[tile], 0, 0, 0);
#pragma unroll
        for (int tile = 0; tile < 2; ++tile)
          accR[tile] = __builtin_amdgcn_mfma_f32_16x16x32_bf16(wFS[tile][kk], af, accR[tile], 0, 0, 0);
      } else {
#pragma unroll
        for (int tile = 0; tile < 2; ++tile)
          accH[tile] = __builtin_amdgcn_mfma_f32_16x16x32_bf16(wSF[tile][kk - 8], af, accH[tile], 0, 0, 0);
#pragma unroll
        for (int tile = 0; tile < 2; ++tile) {
          const int n = wv * 32 + tile * 16 + col;
          const bf16x8 bw = *(const bf16x8*)(lds + W_RES_OFF + n * 512 +
                                             swz(n, (kk - 8) * 64 + kg * 16));
          accR[tile] = __builtin_amdgcn_mfma_f32_16x16x32_bf16(bw, af, accR[tile], 0, 0, 0);
        }
        if (wv == 1) {
          const bf16x8 bp = *(const bf16x8*)(lds + W_PR_OFF + col * 512 +
                                             swz(col, (kk - 8) * 64 + kg * 16));
          accP = __builtin_amdgcn_mfma_f32_16x16x32_bf16(bp, af, accP, 0, 0, 0);
        }
      }
    }
    {  // kk=16: x_t contribution (B-frag from X region; A-frag = W_in)
      const bf16x8 afx = *(const bf16x8*)(lds + X_OFF + col * 128 +
                                          swz(col, kg * 16));
      accH[0] = __builtin_amdgcn_mfma_f32_16x16x32_bf16(wHH[0][8], afx, accH[0], 0, 0, 0);
      accH[1] = __builtin_amdgcn_mfma_f32_16x16x32_bf16(wHH[1][8], afx, accH[1], 0, 0, 0);
    }
    BARRIER();   // all reads of A_s/X done before overwrite (no vmcnt drain)

    // -------- epilogue: update state, store h, restage A_s and X --------
    float* hsT = hs + hsRow + (size_t)t * NH;
    char* rowp = lds + A_S_OFF + col * 1024;
#pragma unroll
    for (int tile = 0; tile < 2; ++tile) {
      const int nb = wv * 32 + tile * 16 + kg * 4;
      f32x4 hv, rv;
#pragma unroll
      for (int j = 0; j < 4; ++j) {
        hv[j] = fmaxf(accH[tile][j], 0.f) + nzc[tile][j];     // alpha_fast = 1
        rv[j] = 0.9f * r_old[tile][j] + 0.1f * fmaxf(accR[tile][j], 0.f);
      }
      r_old[tile] = rv;
      *(f32x4*)(hsT + nb) = hv;                 // fire-and-forget store
      u32x2 hp, rp;
      hp[0] = pk2(hv[0], hv[1]); hp[1] = pk2(hv[2], hv[3]);
      rp[0] = pk2(rv[0], rv[1]); rp[1] = pk2(rv[2], rv[3]);
      *(u32x2*)(rowp + swz(col, nb * 2))       = hp;
      *(u32x2*)(rowp + swz(col, 512 + nb * 2)) = rp;
    }
    if (wv == 7 && kg < 2) {    // restage x(t+1) (kg>=2 zeros persist)
      *(bf16x8*)(lds + X_OFF + col * 128 + swz(col, kg * 16)) = pack8v(xr0, xr1);
    }
    if (wv == 1 && t > 0) {
      f32x4 pv;
#pragma unroll
      for (int j = 0; j < 4; ++j) pv[j] = 1.f / (1.f + __expf(-accP[j]));
      *(f32x4*)(priors + (size_t)(b0 + col) * (LT * 16) + (size_t)(t - 1) * 16 + kg * 4) = pv;
    }

    // -------- reinit accumulators for next step (biases from LDS) --------
#pragma unroll
    for (int tile = 0; tile < 2; ++tile) {
      const int nb = wv * 32 + tile * 16 + kg * 4;
      accH[tile] = *(const f32x4*)(lds + BIASH_OFF + nb * 4);
      accR[tile] = *(const f32x4*)(lds + BIASR_OFF + nb * 4);
    }
    if (wv == 1) accP = *(const f32x4*)(lds + BP_OFF + kg * 16);
    BARRIER();   // A_s/X restaged for next step (no vmcnt drain)
  }

  // -------- tail: prior_{L-1} from staged r_{L-1} --------
  if (wv == 1) {
    f32x4 aP = *(const f32x4*)(lds + BP_OFF + kg * 16);
#pragma unroll
    for (int kk8 = 0; kk8 < 8; ++kk8) {
      const bf16x8 af = *(const bf16x8*)(lds + A_S_OFF + col * 1024 +
                                         swz(col, 512 + kk8 * 64 + kg * 16));
      const bf16x8 bp = *(const bf16x8*)(lds + W_PR_OFF + col * 512 +
                                         swz(col, kk8 * 64 + kg * 16));
      aP = __builtin_amdgcn_mfma_f32_16x16x32_bf16(bp, af, aP, 0, 0, 0);
    }
    f32x4 pv;
#pragma unroll
    for (int j = 0; j < 4; ++j) pv[j] = 1.f / (1.f + __expf(-aP[j]));
    *(f32x4*)(priors + (size_t)(b0 + col) * (LT * 16) + (size_t)(LT - 1) * 16 + kg * 4) = pv;
  }
}

// ===================== kernel 2: out = clip(hs @ W_out^T + b_out) ==========
__global__ __launch_bounds__(256) void out_project_kernel(
    const float* __restrict__ hs,     // [B*L, 256]
    const float* __restrict__ W_out,  // [2, 256]
    const float* __restrict__ b_out,  // [2]
    float* __restrict__ outs)         // [B*L, 2]
{
  const int tid = threadIdx.x;
  const int lane = tid & 63;
  const int wv = tid >> 6;
  const int row0 = blockIdx.x * 64 + wv * 16;   // 16 rows per wave
  f32x4 w0 = *(const f32x4*)(W_out + lane * 4);
  f32x4 w1 = *(const f32x4*)(W_out + 256 + lane * 4);
  const float bo0 = b_out[0], bo1 = b_out[1];
  for (int i = 0; i < 16; ++i) {
    const f32x4 h = *(const f32x4*)(hs + (size_t)(row0 + i) * NH + lane * 4);
    float p0 = h[0]*w0[0] + h[1]*w0[1] + h[2]*w0[2] + h[3]*w0[3];
    float p1 = h[0]*w1[0] + h[1]*w1[1] + h[2]*w1[2] + h[3]*w1[3];
#pragma unroll
    for (int off = 32; off; off >>= 1) {
      p0 += __shfl_down(p0, off, 64);
      p1 += __shfl_down(p1, off, 64);
    }
    if (lane == 0) {
      const size_t o = (size_t)(row0 + i) * 2;
      outs[o]     = fminf(fmaxf(p0 + bo0, -2.f), 2.f);
      outs[o + 1] = fminf(fmaxf(p1 + bo1, -2.f), 2.f);
    }
  }
}

// ===================== launch =====================
extern "C" void kernel_launch(void* const* d_in, const int* in_sizes, int n_in,
                              void* d_out, int out_size, void* d_ws, size_t ws_size,
                              hipStream_t stream) {
  const float* x         = (const float*)d_in[0];
  const float* hidden    = (const float*)d_in[1];
  const float* reservoir = (const float*)d_in[2];
  const float* noise     = (const float*)d_in[3];
  const float* W_in      = (const float*)d_in[4];
  const float* b_in      = (const float*)d_in[5];
  const float* W_hh      = (const float*)d_in[6];
  const float* b_hh      = (const float*)d_in[7];
  const float* W_sf      = (const float*)d_in[8];
  const float* b_sf      = (const float*)d_in[9];
  const float* W_fs      = (const float*)d_in[10];
  const float* b_fs      = (const float*)d_in[11];
  const float* W_res     = (const float*)d_in[12];
  const float* b_res     = (const float*)d_in[13];
  const float* W_out     = (const float*)d_in[14];
  const float* b_out     = (const float*)d_in[15];
  const float* W_pr      = (const float*)d_in[16];
  const float* b_pr      = (const float*)d_in[17];

  float* hs     = (float*)d_out;
  float* outs   = hs + HS_ELEMS;
  float* priors = outs + OUT_ELEMS;

  hipFuncSetAttribute((const void*)rnn_seq_kernel,
                      hipFuncAttributeMaxDynamicSharedMemorySize, LDS_BYTES);
  rnn_seq_kernel<<<4, 512, LDS_BYTES, stream>>>(
      x, hidden, reservoir, noise,
      W_in, b_in, W_hh, b_hh, W_sf, b_sf, W_fs, b_fs,
      W_res, b_res, W_pr, b_pr, hs, priors);

  out_project_kernel<<<2048, 256, 0, stream>>>(hs, W_out, b_out, outs);
}

// Round 5
// 5999.671 us; speedup vs baseline: 1.6163x; 1.6163x over previous
//
#include <hip/hip_runtime.h>
#include <stdint.h>
#include <stddef.h>

// ===================== problem constants =====================
#define LT    2048
#define BATCH 64
#define NH    256
#define HS_ELEMS  (BATCH * LT * NH)   // 33554432
#define OUT_ELEMS (BATCH * LT * 2)    // 262144
// d_out layout: [hs (B,L,256) | outs (B,L,2) | priors (B,L,16)] fp32

typedef __attribute__((ext_vector_type(8))) __bf16 bf16x8;
typedef __attribute__((ext_vector_type(4))) float  f32x4;
typedef __attribute__((ext_vector_type(2))) unsigned u32x2;

// v_cvt_pk_bf16_f32: dst = {lo16: bf16(a), hi16: bf16(b)}, RNE
static __device__ __forceinline__ unsigned pk2(float a, float b) {
  unsigned r;
  asm("v_cvt_pk_bf16_f32 %0, %1, %2" : "=v"(r) : "v"(a), "v"(b));
  return r;
}
static __device__ __forceinline__ bf16x8 pack8v(f32x4 a, f32x4 b) {
  union { unsigned u[4]; bf16x8 v; } r;
  r.u[0] = pk2(a[0], a[1]); r.u[1] = pk2(a[2], a[3]);
  r.u[2] = pk2(b[0], b[1]); r.u[3] = pk2(b[2], b[3]);
  return r.v;
}
static __device__ __forceinline__ bf16x8 pack8(const float* p) {
  return pack8v(*(const f32x4*)p, *(const f32x4*)(p + 4));
}

// Raw workgroup barrier: LDS ordered via lgkmcnt(0); vmcnt deliberately NOT
// drained (global loads/stores stay in flight across the barrier).
#define BARRIER() do {                                           \
    asm volatile("s_waitcnt lgkmcnt(0)" ::: "memory");           \
    __builtin_amdgcn_s_barrier();                                \
    asm volatile("" ::: "memory");                               \
  } while (0)

// LDS layout (bytes): ALL hot data in MFMA-fragment order -> every wave-wide
// LDS op touches consecutive 16B chunks (conflict-free) and uses one address
// register + immediate offsets.
#define W_RES_OFF 0        // frag [kk8][n][kg]: off = kk8*16384 + n*64 + kg*16 (128 KiB)
#define A_S_OFF   131072   // frag [kk][lane]:   off = kk*1024 + lane*16; kk<8 h, kk>=8 r (16 KiB)
#define W_PR_OFF  147456   // frag [kk8][lane]:  off = kk8*1024 + lane*16 (8 KiB)
#define BIASR_OFF 155648   // 64 x f32x4: (b_fs+b_res)
#define BP_OFF    156672   // 4 x f32x4: b_pr
#define LDS_BYTES 156736

// ===================== kernel 1: u = x @ W_in^T + (b_in+b_hh+b_sf) ==========
__global__ __launch_bounds__(256) void u_precompute_kernel(
    const float* __restrict__ x,      // [B, L, 16]
    const float* __restrict__ W_in,   // [256, 16]
    const float* __restrict__ b_in,
    const float* __restrict__ b_hh,
    const float* __restrict__ b_sf,
    float* __restrict__ u)            // [B, L, 256] (= hs region)
{
  __shared__ float xs[64][16];
  const int tid = threadIdx.x;
  const int b  = blockIdx.x >> 5;
  const int tc = (blockIdx.x & 31) << 6;   // 64 timesteps per block
  float w[16];
#pragma unroll
  for (int i = 0; i < 16; ++i) w[i] = W_in[tid * 16 + i];
  const float bias = b_in[tid] + b_hh[tid] + b_sf[tid];
  for (int r = tid; r < 64 * 16; r += 256)
    xs[r >> 4][r & 15] = x[((size_t)b * LT + tc + (r >> 4)) * 16 + (r & 15)];
  __syncthreads();
  for (int tt = 0; tt < 64; ++tt) {
    float s = bias;
#pragma unroll
    for (int i = 0; i < 16; ++i) s += xs[tt][i] * w[i];
    u[((size_t)b * LT + tc + tt) * NH + tid] = s;
  }
}

// ===================== kernel 2: the serial recurrence =====================
// 8 waves x 64 lanes; wave owns 32 output cols (2 tiles of 16) for tmp_h and
// tmp_r. Weights = MFMA A-operand (VGPR/AGPR), state = B-operand (LDS bf16,
// fragment-order layout). lgkm-only barriers; u(t+1)/noise(t) prefetched at
// K-loop start, consumed in the epilogue.
__global__ __launch_bounds__(512, 1) void rnn_seq_kernel(
    const float* __restrict__ hidden,     // [B,256]
    const float* __restrict__ reservoir,  // [B,256]
    const float* __restrict__ noise,      // [L,B,256]
    const float* __restrict__ W_hh, const float* __restrict__ W_sf,
    const float* __restrict__ W_fs, const float* __restrict__ W_res,
    const float* __restrict__ b_fs, const float* __restrict__ b_res,
    const float* __restrict__ W_pr, const float* __restrict__ b_pr,
    float* __restrict__ hs,               // [B,L,256] (holds u on entry)
    float* __restrict__ priors)           // [B,L,16]
{
  extern __shared__ char lds[];
  const int tid  = threadIdx.x;
  const int lane = tid & 63;
  const int wv   = tid >> 6;        // wave 0..7
  const int col  = lane & 15;       // batch row within WG
  const int kg   = lane >> 4;       // k-group 0..3
  const int b0   = blockIdx.x * 16;

  // ---- stage W_res into frag layout: chunk c -> addr c*16 (coalesced) ----
  // c = kk8*1024 + n*4 + kg ; src k = kk8*32 + kg*8
#pragma unroll 4
  for (int j = 0; j < 16; ++j) {
    const int c   = j * 512 + tid;
    const int kk8 = c >> 10, n = (c >> 2) & 255, kgs = c & 3;
    *(bf16x8*)(lds + W_RES_OFF + c * 16) =
        pack8(W_res + (size_t)n * NH + kk8 * 32 + kgs * 8);
  }
  // ---- stage W_pr frag: c = kk8*64 + lane16 -> addr c*16; n = col idx ----
  {
    const int kk8 = tid >> 6, l16 = tid & 63;
    const int kgs = l16 >> 4, n = l16 & 15;
    *(bf16x8*)(lds + W_PR_OFF + tid * 16) =
        pack8(W_pr + (size_t)n * NH + kk8 * 32 + kgs * 8);
  }
  // ---- stage initial state h0 (c=tid) and r0 (c=tid+512) ----
  {
    const int kk = tid >> 6, l16 = tid & 63;
    const int kgs = l16 >> 4, m = l16 & 15;
    *(bf16x8*)(lds + A_S_OFF + tid * 16) =
        pack8(hidden + (size_t)(b0 + m) * NH + kk * 32 + kgs * 8);
    *(bf16x8*)(lds + A_S_OFF + (tid + 512) * 16) =
        pack8(reservoir + (size_t)(b0 + m) * NH + kk * 32 + kgs * 8);
  }
  // ---- stage biases: (b_fs+b_res) as 64 f32x4; b_pr as 4 f32x4 ----
  if (tid < 64) {
    f32x4 v = *(const f32x4*)(b_fs + tid * 4);
    f32x4 w = *(const f32x4*)(b_res + tid * 4);
    *(f32x4*)(lds + BIASR_OFF + tid * 16) = v + w;
  }
  if (tid < 4)
    *(f32x4*)(lds + BP_OFF + tid * 16) = *(const f32x4*)(b_pr + tid * 4);

  // ---- per-lane weight fragments (A-operand), 2 tiles per wave ----
  bf16x8 wHH[2][8], wSF[2][8], wFS[2][8];
#pragma unroll
  for (int tile = 0; tile < 2; ++tile) {
    const int n = wv * 32 + tile * 16 + col;
#pragma unroll
    for (int kk = 0; kk < 8; ++kk) {
      wHH[tile][kk] = pack8(W_hh + (size_t)n * NH + kk * 32 + kg * 8);
      wSF[tile][kk] = pack8(W_sf + (size_t)n * NH + kk * 32 + kg * 8);
      wFS[tile][kk] = pack8(W_fs + (size_t)n * NH + kk * 32 + kg * 8);
    }
  }

  // ---- state / accumulators ----
  const size_t hsRow = (size_t)(b0 + col) * (LT * NH);
  const size_t nzRow = (size_t)(b0 + col) * NH;
  f32x4 r_old[2], accH[2], accR[2], accP;
#pragma unroll
  for (int tile = 0; tile < 2; ++tile) {
    const int nb = wv * 32 + tile * 16 + kg * 4;
    r_old[tile] = *(const f32x4*)(reservoir + nzRow + nb);
    accH[tile]  = *(const f32x4*)(hs + hsRow + nb);                 // u(0)
    accR[tile]  = *(const f32x4*)(lds + BIASR_OFF + nb * 4);
  }
  accP = *(const f32x4*)(lds + BP_OFF + kg * 16);

  BARRIER();   // staging visible to all waves

#pragma unroll 1
  for (int t = 0; t < LT; ++t) {
    // ---- issue global prefetch: u(t+1) and noise(t); consumed in epilogue --
    const size_t tp1 = (t + 1 < LT) ? (size_t)(t + 1) : (size_t)(LT - 1);
    f32x4 pfU[2], nzc[2];
#pragma unroll
    for (int tile = 0; tile < 2; ++tile) {
      const int nb = wv * 32 + tile * 16 + kg * 4;
      pfU[tile] = *(const f32x4*)(hs + hsRow + tp1 * NH + nb);
      nzc[tile] = *(const f32x4*)(noise + (size_t)t * (BATCH * NH) + nzRow + nb);
    }

    // -------- K-loop: K=512 over [h | r], 16 k-steps --------
    const char* afp = lds + A_S_OFF + lane * 16;          // + kk*1024 imm
    const char* bwp = lds + W_RES_OFF + (wv * 32) * 64 + col * 64 + kg * 16;
    const char* bpp = lds + W_PR_OFF + lane * 16;
#pragma unroll
    for (int kk = 0; kk < 16; ++kk) {
      const bf16x8 af = *(const bf16x8*)(afp + kk * 1024);
      if (kk < 8) {
#pragma unroll
        for (int tile = 0; tile < 2; ++tile)
          accH[tile] = __builtin_amdgcn_mfma_f32_16x16x32_bf16(wHH[tile][kk], af, accH[tile], 0, 0, 0);
#pragma unroll
        for (int tile = 0; tile < 2; ++tile)
          accR[tile] = __builtin_amdgcn_mfma_f32_16x16x32_bf16(wFS[tile][kk], af, accR[tile], 0, 0, 0);
      } else {
#pragma unroll
        for (int tile = 0; tile < 2; ++tile)
          accH[tile] = __builtin_amdgcn_mfma_f32_16x16x32_bf16(wSF[tile][kk - 8], af, accH[tile], 0, 0, 0);
#pragma unroll
        for (int tile = 0; tile < 2; ++tile) {
          const bf16x8 bw = *(const bf16x8*)(bwp + (kk - 8) * 16384 + tile * 1024);
          accR[tile] = __builtin_amdgcn_mfma_f32_16x16x32_bf16(bw, af, accR[tile], 0, 0, 0);
        }
        if (wv == 1) {
          const bf16x8 bp = *(const bf16x8*)(bpp + (kk - 8) * 1024);
          accP = __builtin_amdgcn_mfma_f32_16x16x32_bf16(bp, af, accP, 0, 0, 0);
        }
      }
    }
    BARRIER();   // all reads of A_s done before overwrite (no vmcnt drain)

    // -------- epilogue: update state, store h, restage A_s (frag order) ----
    // h element n -> chunk kk=wv, sub-chunk kg'=2*tile+(kg>>1), byte 8*(kg&1)
    float* hsT = hs + hsRow + (size_t)t * NH;
    char* abase = lds + A_S_OFF + wv * 1024 + col * 16 + (kg & 1) * 8;
#pragma unroll
    for (int tile = 0; tile < 2; ++tile) {
      const int nb = wv * 32 + tile * 16 + kg * 4;
      f32x4 hv, rv;
#pragma unroll
      for (int j = 0; j < 4; ++j) {
        hv[j] = fmaxf(accH[tile][j], 0.f) + nzc[tile][j];     // alpha_fast = 1
        rv[j] = 0.9f * r_old[tile][j] + 0.1f * fmaxf(accR[tile][j], 0.f);
      }
      r_old[tile] = rv;
      *(f32x4*)(hsT + nb) = hv;                 // fire-and-forget store
      u32x2 hp, rp;
      hp[0] = pk2(hv[0], hv[1]); hp[1] = pk2(hv[2], hv[3]);
      rp[0] = pk2(rv[0], rv[1]); rp[1] = pk2(rv[2], rv[3]);
      char* dst = abase + (2 * tile + (kg >> 1)) * 256;
      *(u32x2*)dst          = hp;
      *(u32x2*)(dst + 8192) = rp;               // r chunks at kk+8
    }
    if (wv == 1 && t > 0) {
      f32x4 pv;
#pragma unroll
      for (int j = 0; j < 4; ++j) pv[j] = 1.f / (1.f + __expf(-accP[j]));
      *(f32x4*)(priors + (size_t)(b0 + col) * (LT * 16) + (size_t)(t - 1) * 16 + kg * 4) = pv;
    }

    // -------- reinit accumulators for next step --------
#pragma unroll
    for (int tile = 0; tile < 2; ++tile) {
      const int nb = wv * 32 + tile * 16 + kg * 4;
      accH[tile] = pfU[tile];                                   // u(t+1)
      accR[tile] = *(const f32x4*)(lds + BIASR_OFF + nb * 4);
    }
    accP = *(const f32x4*)(lds + BP_OFF + kg * 16);
    BARRIER();   // A_s restaged for next step (no vmcnt drain)
  }

  // -------- tail: prior_{L-1} from staged r_{L-1} --------
  if (wv == 1) {
    f32x4 aP = *(const f32x4*)(lds + BP_OFF + kg * 16);
    const char* afp = lds + A_S_OFF + 8192 + lane * 16;   // r chunks
    const char* bpp = lds + W_PR_OFF + lane * 16;
#pragma unroll
    for (int kk8 = 0; kk8 < 8; ++kk8) {
      const bf16x8 af = *(const bf16x8*)(afp + kk8 * 1024);
      const bf16x8 bp = *(const bf16x8*)(bpp + kk8 * 1024);
      aP = __builtin_amdgcn_mfma_f32_16x16x32_bf16(bp, af, aP, 0, 0, 0);
    }
    f32x4 pv;
#pragma unroll
    for (int j = 0; j < 4; ++j) pv[j] = 1.f / (1.f + __expf(-aP[j]));
    *(f32x4*)(priors + (size_t)(b0 + col) * (LT * 16) + (size_t)(LT - 1) * 16 + kg * 4) = pv;
  }
}

// ===================== kernel 3: out = clip(hs @ W_out^T + b_out) ==========
__global__ __launch_bounds__(256) void out_project_kernel(
    const float* __restrict__ hs,     // [B*L, 256]
    const float* __restrict__ W_out,  // [2, 256]
    const float* __restrict__ b_out,  // [2]
    float* __restrict__ outs)         // [B*L, 2]
{
  const int tid = threadIdx.x;
  const int lane = tid & 63;
  const int wv = tid >> 6;
  const int row0 = blockIdx.x * 64 + wv * 16;   // 16 rows per wave
  f32x4 w0 = *(const f32x4*)(W_out + lane * 4);
  f32x4 w1 = *(const f32x4*)(W_out + 256 + lane * 4);
  const float bo0 = b_out[0], bo1 = b_out[1];
  for (int i = 0; i < 16; ++i) {
    const f32x4 h = *(const f32x4*)(hs + (size_t)(row0 + i) * NH + lane * 4);
    float p0 = h[0]*w0[0] + h[1]*w0[1] + h[2]*w0[2] + h[3]*w0[3];
    float p1 = h[0]*w1[0] + h[1]*w1[1] + h[2]*w1[2] + h[3]*w1[3];
#pragma unroll
    for (int off = 32; off; off >>= 1) {
      p0 += __shfl_down(p0, off, 64);
      p1 += __shfl_down(p1, off, 64);
    }
    if (lane == 0) {
      const size_t o = (size_t)(row0 + i) * 2;
      outs[o]     = fminf(fmaxf(p0 + bo0, -2.f), 2.f);
      outs[o + 1] = fminf(fmaxf(p1 + bo1, -2.f), 2.f);
    }
  }
}

// ===================== launch =====================
extern "C" void kernel_launch(void* const* d_in, const int* in_sizes, int n_in,
                              void* d_out, int out_size, void* d_ws, size_t ws_size,
                              hipStream_t stream) {
  const float* x         = (const float*)d_in[0];
  const float* hidden    = (const float*)d_in[1];
  const float* reservoir = (const float*)d_in[2];
  const float* noise     = (const float*)d_in[3];
  const float* W_in      = (const float*)d_in[4];
  const float* b_in      = (const float*)d_in[5];
  const float* W_hh      = (const float*)d_in[6];
  const float* b_hh      = (const float*)d_in[7];
  const float* W_sf      = (const float*)d_in[8];
  const float* b_sf      = (const float*)d_in[9];
  const float* W_fs      = (const float*)d_in[10];
  const float* b_fs      = (const float*)d_in[11];
  const float* W_res     = (const float*)d_in[12];
  const float* b_res     = (const float*)d_in[13];
  const float* W_out     = (const float*)d_in[14];
  const float* b_out     = (const float*)d_in[15];
  const float* W_pr      = (const float*)d_in[16];
  const float* b_pr      = (const float*)d_in[17];

  float* hs     = (float*)d_out;
  float* outs   = hs + HS_ELEMS;
  float* priors = outs + OUT_ELEMS;

  u_precompute_kernel<<<2048, 256, 0, stream>>>(x, W_in, b_in, b_hh, b_sf, hs);

  hipFuncSetAttribute((const void*)rnn_seq_kernel,
                      hipFuncAttributeMaxDynamicSharedMemorySize, LDS_BYTES);
  rnn_seq_kernel<<<4, 512, LDS_BYTES, stream>>>(
      hidden, reservoir, noise, W_hh, W_sf, W_fs, W_res,
      b_fs, b_res, W_pr, b_pr, hs, priors);

  out_project_kernel<<<2048, 256, 0, stream>>>(hs, W_out, b_out, outs);
}